// Round 1
// baseline (2837.680 us; speedup 1.0000x reference)
//
#include <hip/hip_runtime.h>
#include <cmath>

#define NUM_FEAT 128
#define NUM_RADIAL 6

// ---------------------------------------------------------------------------
// Kernel 1: per-edge rbf projection + scatter-add into atom accumulator.
// Layout: 32 lanes per edge, each lane handles 4 consecutive features.
// Block = 256 threads = 8 edges. Grid-stride so the per-thread W_rbf register
// preload (24 floats) amortizes over ~50 edges.
// ---------------------------------------------------------------------------
__global__ __launch_bounds__(256) void edge_scatter_kernel(
    const float* __restrict__ m, const float* __restrict__ rbf,
    const int* __restrict__ idx, const float* __restrict__ W_rbf,
    float* __restrict__ atom_feat, int E)
{
    const int tid   = threadIdx.x;
    const int fc    = tid & 31;   // feature chunk -> features 4*fc .. 4*fc+3
    const int eslot = tid >> 5;   // 0..7 edge slot within block

    // Preload this lane's 4 rows of W_rbf (stays in registers across edges).
    float wr[4][NUM_RADIAL];
#pragma unroll
    for (int k = 0; k < 4; ++k)
#pragma unroll
        for (int r = 0; r < NUM_RADIAL; ++r)
            wr[k][r] = W_rbf[(4 * fc + k) * NUM_RADIAL + r];

    const long estride = (long)gridDim.x * 8;
    for (long e = (long)blockIdx.x * 8 + eslot; e < E; e += estride) {
        // rbf[e][0..5]: row is 24 B, 8-byte aligned -> three float2 loads
        const float2* rp = (const float2*)(rbf + e * NUM_RADIAL);
        float2 r01 = rp[0], r23 = rp[1], r45 = rp[2];
        float rv[6] = {r01.x, r01.y, r23.x, r23.y, r45.x, r45.y};

        float4 mv = *(const float4*)(m + e * NUM_FEAT + fc * 4);
        int a = idx[e];

        float o[4];
#pragma unroll
        for (int k = 0; k < 4; ++k) {
            float s = 0.f;
#pragma unroll
            for (int r = 0; r < NUM_RADIAL; ++r)
                s = fmaf(rv[r], wr[k][r], s);
            o[k] = s;
        }

        float* dst = atom_feat + (long)a * NUM_FEAT + fc * 4;
        unsafeAtomicAdd(dst + 0, mv.x * o[0]);
        unsafeAtomicAdd(dst + 1, mv.y * o[1]);
        unsafeAtomicAdd(dst + 2, mv.z * o[2]);
        unsafeAtomicAdd(dst + 3, mv.w * o[3]);
    }
}

// ---------------------------------------------------------------------------
// Kernel 2: per-atom MLP  out = swish(swish(af) @ W1.T + b1) @ W2.T + b2
// Block = 256 threads handles 16 atoms. W1 staged transposed in LDS
// (W1t[f][j], conflict-free float4 reads). Activations swish-ed into padded
// LDS. Each 16-lane group owns one atom; lane lj computes h[4*lj..4*lj+3].
// ---------------------------------------------------------------------------
__global__ __launch_bounds__(256) void mlp_kernel(
    const float* __restrict__ atom_feat, const float* __restrict__ W1,
    const float* __restrict__ b1, const float* __restrict__ W2,
    const float* __restrict__ b2, float* __restrict__ out, int N)
{
    __shared__ float W1t[128][64];   // 32 KB, transposed W1
    __shared__ float sbuf[16][132];  // padded: breaks 4-way bank alias on s

    const int t = threadIdx.x;

    // Stage W1 transposed: W1 is [64][128] row-major.
    for (int k = t; k < 64 * 128; k += 256) {
        int j = k >> 7, f = k & 127;
        W1t[f][j] = W1[k];
    }

    // Stage 16 atom rows, applying swish on the way in. Coalesced.
    const int nb = blockIdx.x * 16;
    for (int k = t; k < 16 * 128; k += 256) {
        int a = k >> 7, f = k & 127;
        int n = nb + a;
        float v = (n < N) ? atom_feat[(long)n * NUM_FEAT + f] : 0.f;
        sbuf[a][f] = v / (1.f + __expf(-v));
    }
    __syncthreads();

    const int lane = t & 63;
    const int wave = t >> 6;
    const int ag   = lane >> 4;  // atom within wave: 0..3
    const int lj   = lane & 15;  // j-group: outputs 4*lj .. 4*lj+3
    const int a    = wave * 4 + ag;
    const int n    = nb + a;

    float4 bv = *(const float4*)(b1 + 4 * lj);
    float a0 = bv.x, a1 = bv.y, a2 = bv.z, a3 = bv.w;

#pragma unroll 4
    for (int f = 0; f < 128; ++f) {
        float s  = sbuf[a][f];
        float4 w = *(const float4*)&W1t[f][4 * lj];
        a0 = fmaf(s, w.x, a0);
        a1 = fmaf(s, w.y, a1);
        a2 = fmaf(s, w.z, a2);
        a3 = fmaf(s, w.w, a3);
    }

    float4 w2 = *(const float4*)(W2 + 4 * lj);
    float r = (a0 / (1.f + __expf(-a0))) * w2.x
            + (a1 / (1.f + __expf(-a1))) * w2.y
            + (a2 / (1.f + __expf(-a2))) * w2.z
            + (a3 / (1.f + __expf(-a3))) * w2.w;

    // reduce over the 16 lanes of this atom group
    r += __shfl_xor(r, 1);
    r += __shfl_xor(r, 2);
    r += __shfl_xor(r, 4);
    r += __shfl_xor(r, 8);

    if (lj == 0 && n < N) out[n] = r + b2[0];
}

extern "C" void kernel_launch(void* const* d_in, const int* in_sizes, int n_in,
                              void* d_out, int out_size, void* d_ws, size_t ws_size,
                              hipStream_t stream) {
    const float* m     = (const float*)d_in[0];
    const float* rbf   = (const float*)d_in[1];
    const int*   idx   = (const int*)d_in[2];
    // d_in[3] = num_atoms (device scalar; N taken from out_size instead)
    const float* W_rbf = (const float*)d_in[4];
    const float* W1    = (const float*)d_in[5];
    const float* b1    = (const float*)d_in[6];
    const float* W2    = (const float*)d_in[7];
    const float* b2    = (const float*)d_in[8];
    float* out = (float*)d_out;

    const int E = in_sizes[0] / NUM_FEAT;
    const int N = out_size;  // out is [N, 1]

    float* atom_feat = (float*)d_ws;  // N*128 floats = 51.2 MB scratch

    hipMemsetAsync(atom_feat, 0, (size_t)N * NUM_FEAT * sizeof(float), stream);

    edge_scatter_kernel<<<4096, 256, 0, stream>>>(m, rbf, idx, W_rbf, atom_feat, E);

    mlp_kernel<<<(N + 15) / 16, 256, 0, stream>>>(atom_feat, W1, b1, W2, b2, out, N);
}

// Round 2
// 702.963 us; speedup vs baseline: 4.0367x; 4.0367x over previous
//
#include <hip/hip_runtime.h>

#define NF 128
#define NR 6

// ---------------------------------------------------------------------------
// Counting-sort passes: histogram -> scan -> reorder (edge ids + rbf payload
// copied into segment order so the gather kernel reads sequentially).
// ---------------------------------------------------------------------------
__global__ __launch_bounds__(256) void hist_kernel(
    const int* __restrict__ idx, int* __restrict__ count, int E)
{
    int stride = gridDim.x * blockDim.x;
    for (int e = blockIdx.x * blockDim.x + threadIdx.x; e < E; e += stride)
        atomicAdd(&count[idx[e]], 1);
}

__global__ __launch_bounds__(1024) void scan_kernel(
    const int* __restrict__ count, int* __restrict__ offsets,
    int* __restrict__ cursor, int N)
{
    __shared__ int ssum[1024];
    const int t = threadIdx.x;
    const int chunk = (N + 1023) / 1024;
    const int lo = t * chunk;
    const int hi = min(lo + chunk, N);

    int s = 0;
    for (int k = lo; k < hi; ++k) s += count[k];
    ssum[t] = s;
    __syncthreads();
    for (int d = 1; d < 1024; d <<= 1) {
        int v = (t >= d) ? ssum[t - d] : 0;
        __syncthreads();
        ssum[t] += v;
        __syncthreads();
    }
    int run = ssum[t] - s;  // exclusive prefix of this thread's chunk
    for (int k = lo; k < hi; ++k) {
        offsets[k] = run;
        cursor[k]  = run;
        run += count[k];
    }
    if (t == 0) offsets[N] = ssum[1023];
}

__global__ __launch_bounds__(256) void reorder_kernel(
    const int* __restrict__ idx, const float* __restrict__ rbf,
    int* __restrict__ cursor, int* __restrict__ sorted,
    float* __restrict__ srbf, int E)
{
    long stride = (long)gridDim.x * blockDim.x;
    for (long e = blockIdx.x * blockDim.x + threadIdx.x; e < E; e += stride) {
        int a = idx[e];
        int pos = atomicAdd(&cursor[a], 1);
        sorted[pos] = (int)e;
        const float2* rp = (const float2*)(rbf + e * NR);
        float2 r0 = rp[0], r1 = rp[1], r2 = rp[2];
        float2* dp = (float2*)(srbf + (long)pos * NR);  // pos*24B -> 8B aligned
        dp[0] = r0; dp[1] = r1; dp[2] = r2;
    }
}

// ---------------------------------------------------------------------------
// Fused gather + rbf-projection + per-atom MLP.
// Block = 256 (4 waves), 16 atoms/block, 1 wave per atom x4 sequential.
// Per atom: 64 lanes each own features 2*lane, 2*lane+1; edges pipelined in
// chunks of 4 (ids pre-loaded into a register cache, broadcast via shfl).
// Then swish -> LDS, layer1 with W1 transposed in LDS, shfl-reduce layer2.
// ---------------------------------------------------------------------------
#define APW 4  // atoms per wave

__global__ __launch_bounds__(256) void gather_mlp_kernel(
    const float* __restrict__ m, const int* __restrict__ offsets,
    const int* __restrict__ sorted, const float* __restrict__ srbf,
    const float* __restrict__ W_rbf, const float* __restrict__ W1,
    const float* __restrict__ b1, const float* __restrict__ W2,
    const float* __restrict__ b2, float* __restrict__ out, int N)
{
    __shared__ float W1t[128][68];   // transposed W1, padded: float4 reads ok,
                                     // 8-way (not 64-way) staging-write conflict
    __shared__ float sb[4][APW][132];

    const int t = threadIdx.x;
    const int lane = t & 63;
    const int w = t >> 6;

    // stage W1 transposed (W1 is [64][128] row-major; global read coalesced)
    for (int k = t; k < 64 * 128; k += 256) {
        int j = k >> 7, f = k & 127;
        W1t[f][j] = W1[k];
    }

    // per-lane W_rbf rows for features 2*lane, 2*lane+1 (held in registers)
    float wr0[NR], wr1[NR];
#pragma unroll
    for (int r = 0; r < NR; ++r) {
        wr0[r] = W_rbf[(2 * lane + 0) * NR + r];
        wr1[r] = W_rbf[(2 * lane + 1) * NR + r];
    }

    __syncthreads();

    const int nb = blockIdx.x * (4 * APW) + w * APW;

    for (int ta = 0; ta < APW; ++ta) {
        int n = nb + ta;
        float acc0 = 0.f, acc1 = 0.f;
        if (n < N) {
            int beg = offsets[n];
            int end = offsets[n + 1];
            // register cache of up to 64 edge ids (one coalesced load)
            int eid = (beg + lane < end) ? sorted[beg + lane] : 0;
            for (int p0 = beg; p0 < end; p0 += 4) {
                int cnt = end - p0; if (cnt > 4) cnt = 4;
                int e4[4];
                float2 mv[4];
                float2 rv[4][3];
#pragma unroll
                for (int k = 0; k < 4; ++k) {
                    int off = p0 - beg + k;
                    int e;
                    if (off < 64) e = __shfl(eid, off);
                    else e = (p0 + k < end) ? sorted[p0 + k] : __shfl(eid, 0);
                    if (k >= cnt) e = __shfl(eid, 0);  // clamp to a safe row
                    e4[k] = e;
                }
#pragma unroll
                for (int k = 0; k < 4; ++k) {
                    mv[k] = *(const float2*)(m + (long)e4[k] * NF + lane * 2);
                    const float2* rp =
                        (const float2*)(srbf + (long)(p0 + (k < cnt ? k : 0)) * NR);
                    rv[k][0] = rp[0]; rv[k][1] = rp[1]; rv[k][2] = rp[2];
                }
#pragma unroll
                for (int k = 0; k < 4; ++k) {
                    if (k < cnt) {
                        float f0 = rv[k][0].x * wr0[0];
                        float f1 = rv[k][0].x * wr1[0];
                        f0 = fmaf(rv[k][0].y, wr0[1], f0);
                        f1 = fmaf(rv[k][0].y, wr1[1], f1);
                        f0 = fmaf(rv[k][1].x, wr0[2], f0);
                        f1 = fmaf(rv[k][1].x, wr1[2], f1);
                        f0 = fmaf(rv[k][1].y, wr0[3], f0);
                        f1 = fmaf(rv[k][1].y, wr1[3], f1);
                        f0 = fmaf(rv[k][2].x, wr0[4], f0);
                        f1 = fmaf(rv[k][2].x, wr1[4], f1);
                        f0 = fmaf(rv[k][2].y, wr0[5], f0);
                        f1 = fmaf(rv[k][2].y, wr1[5], f1);
                        acc0 = fmaf(mv[k].x, f0, acc0);
                        acc1 = fmaf(mv[k].y, f1, acc1);
                    }
                }
            }
        }
        float s0 = acc0 / (1.f + __expf(-acc0));
        float s1 = acc1 / (1.f + __expf(-acc1));
        *(float2*)&sb[w][ta][2 * lane] = make_float2(s0, s1);
    }

    // layer 1 for this wave's 4 atoms together:
    // 16-lane group `ag` = atom, lane lj owns outputs 4*lj..4*lj+3
    const int ag = lane >> 4;
    const int lj = lane & 15;

    float4 bv = *(const float4*)(b1 + 4 * lj);
    float h0 = bv.x, h1 = bv.y, h2 = bv.z, h3 = bv.w;

    for (int f = 0; f < 128; f += 4) {
        float4 sv = *(const float4*)&sb[w][ag][f];
        float4 w0 = *(const float4*)&W1t[f + 0][4 * lj];
        float4 w1v = *(const float4*)&W1t[f + 1][4 * lj];
        float4 w2v = *(const float4*)&W1t[f + 2][4 * lj];
        float4 w3v = *(const float4*)&W1t[f + 3][4 * lj];
        h0 = fmaf(sv.x, w0.x, h0);  h1 = fmaf(sv.x, w0.y, h1);
        h2 = fmaf(sv.x, w0.z, h2);  h3 = fmaf(sv.x, w0.w, h3);
        h0 = fmaf(sv.y, w1v.x, h0); h1 = fmaf(sv.y, w1v.y, h1);
        h2 = fmaf(sv.y, w1v.z, h2); h3 = fmaf(sv.y, w1v.w, h3);
        h0 = fmaf(sv.z, w2v.x, h0); h1 = fmaf(sv.z, w2v.y, h1);
        h2 = fmaf(sv.z, w2v.z, h2); h3 = fmaf(sv.z, w2v.w, h3);
        h0 = fmaf(sv.w, w3v.x, h0); h1 = fmaf(sv.w, w3v.y, h1);
        h2 = fmaf(sv.w, w3v.z, h2); h3 = fmaf(sv.w, w3v.w, h3);
    }

    float4 w2 = *(const float4*)(W2 + 4 * lj);
    float r = (h0 / (1.f + __expf(-h0))) * w2.x
            + (h1 / (1.f + __expf(-h1))) * w2.y
            + (h2 / (1.f + __expf(-h2))) * w2.z
            + (h3 / (1.f + __expf(-h3))) * w2.w;

    r += __shfl_xor(r, 1);
    r += __shfl_xor(r, 2);
    r += __shfl_xor(r, 4);
    r += __shfl_xor(r, 8);

    int n = nb + ag;
    if (lj == 0 && n < N) out[n] = r + b2[0];
}

extern "C" void kernel_launch(void* const* d_in, const int* in_sizes, int n_in,
                              void* d_out, int out_size, void* d_ws, size_t ws_size,
                              hipStream_t stream) {
    const float* m     = (const float*)d_in[0];
    const float* rbf   = (const float*)d_in[1];
    const int*   idx   = (const int*)d_in[2];
    const float* W_rbf = (const float*)d_in[4];
    const float* W1    = (const float*)d_in[5];
    const float* b1    = (const float*)d_in[6];
    const float* W2    = (const float*)d_in[7];
    const float* b2    = (const float*)d_in[8];
    float* out = (float*)d_out;

    const int E = in_sizes[2];   // i has one entry per edge
    const int N = out_size;      // out is [N, 1]

    // workspace layout (ints; all segment starts even -> 8B alignment)
    int* count   = (int*)d_ws;                       // N
    int* offsets = count + N;                        // N+1
    int* cursor  = offsets + ((N + 2) & ~1);         // N
    int* sorted  = cursor + N;                       // E
    float* srbf  = (float*)(sorted + ((E + 1) & ~1)); // 6E floats
    // total ~46 MB for N=100K, E=1.6M

    hipMemsetAsync(count, 0, (size_t)N * sizeof(int), stream);

    hist_kernel<<<2048, 256, 0, stream>>>(idx, count, E);
    scan_kernel<<<1, 1024, 0, stream>>>(count, offsets, cursor, N);
    reorder_kernel<<<2048, 256, 0, stream>>>(idx, rbf, cursor, sorted, srbf, E);
    gather_mlp_kernel<<<(N + 15) / 16, 256, 0, stream>>>(
        m, offsets, sorted, srbf, W_rbf, W1, b1, W2, b2, out, N);
}

// Round 3
// 470.517 us; speedup vs baseline: 6.0310x; 1.4940x over previous
//
#include <hip/hip_runtime.h>

#define NF 128
#define NR 6

// ---------------------------------------------------------------------------
// Pass 1: histogram of atom indices.
// ---------------------------------------------------------------------------
__global__ __launch_bounds__(256) void hist_kernel(
    const int* __restrict__ idx, int* __restrict__ count, int E)
{
    int stride = gridDim.x * blockDim.x;
    for (int e = blockIdx.x * blockDim.x + threadIdx.x; e < E; e += stride)
        atomicAdd(&count[idx[e]], 1);
}

// ---------------------------------------------------------------------------
// Pass 2: exclusive scan, one dispatch, 256 blocks.
// Block b computes base = sum(count[0..lo)) with coalesced block-stride reads
// (redundant but L2-resident and parallel), then tile-scans its own chunk.
// ---------------------------------------------------------------------------
#define SCAN_BLOCKS 256

__global__ __launch_bounds__(256) void scan_all_kernel(
    const int* __restrict__ count, int* __restrict__ offsets,
    int* __restrict__ cursor, int N)
{
    __shared__ int red[256];
    __shared__ int tile[256];
    const int b = blockIdx.x, t = threadIdx.x;
    const int chunk = (N + SCAN_BLOCKS - 1) / SCAN_BLOCKS;
    const int lo = b * chunk;
    const int hi = min(lo + chunk, N);

    // base = sum of all counts before this block's chunk
    int s = 0;
    for (int i = t; i < lo; i += 256) s += count[i];
    red[t] = s;
    __syncthreads();
    for (int d = 128; d > 0; d >>= 1) {
        if (t < d) red[t] += red[t + d];
        __syncthreads();
    }
    int base = red[0];

    // scan own chunk in tiles of 256
    for (int p = lo; p < hi; p += 256) {
        int v = (p + t < hi) ? count[p + t] : 0;
        tile[t] = v;
        __syncthreads();
        for (int d = 1; d < 256; d <<= 1) {
            int u = (t >= d) ? tile[t - d] : 0;
            __syncthreads();
            tile[t] += u;
            __syncthreads();
        }
        if (p + t < hi) {
            int excl = base + tile[t] - v;
            offsets[p + t] = excl;
            cursor[p + t]  = excl;
            if (p + t == N - 1) offsets[N] = excl + v;
        }
        base += tile[255];
        __syncthreads();  // protect tile[] before next iteration's overwrite
    }
}

// ---------------------------------------------------------------------------
// Pass 3: reorder edge ids + rbf payload into segment order.
// ---------------------------------------------------------------------------
__global__ __launch_bounds__(256) void reorder_kernel(
    const int* __restrict__ idx, const float* __restrict__ rbf,
    int* __restrict__ cursor, int* __restrict__ sorted,
    float* __restrict__ srbf, int E)
{
    long stride = (long)gridDim.x * blockDim.x;
    for (long e = blockIdx.x * blockDim.x + threadIdx.x; e < E; e += stride) {
        int a = idx[e];
        int pos = atomicAdd(&cursor[a], 1);
        sorted[pos] = (int)e;
        const float2* rp = (const float2*)(rbf + e * NR);
        float2 r0 = rp[0], r1 = rp[1], r2 = rp[2];
        float2* dp = (float2*)(srbf + (long)pos * NR);
        dp[0] = r0; dp[1] = r1; dp[2] = r2;
    }
}

// ---------------------------------------------------------------------------
// Pass 4: fused gather + rbf projection + per-atom MLP.
// Block = 256 = 4 waves, 16 atoms/block. Each wave processes 2 atoms in
// PARALLEL (32-lane halves) x 2 sequential iterations. Half-wave lane hl owns
// features 4*hl..4*hl+3 (float4 m loads, 512 B/edge). Edge ids cached in
// registers (32-deep) and broadcast via shfl; 4-deep load pipeline per half
// (8 m-loads in flight per wave). Then swish -> LDS, layer1 with W1
// transposed in LDS, shfl-reduce layer2.
// ---------------------------------------------------------------------------
__global__ __launch_bounds__(256) void gather_mlp_kernel(
    const float* __restrict__ m, const int* __restrict__ offsets,
    const int* __restrict__ sorted, const float* __restrict__ srbf,
    const float* __restrict__ W_rbf, const float* __restrict__ W1,
    const float* __restrict__ b1, const float* __restrict__ W2,
    const float* __restrict__ b2, float* __restrict__ out, int N)
{
    __shared__ float W1t[128][68];   // transposed W1, padded
    __shared__ float sb[4][4][132];  // [wave][atom][feat], padded

    const int t = threadIdx.x;
    const int lane = t & 63;
    const int w = t >> 6;
    const int h  = lane >> 5;   // half-wave: 0/1
    const int hl = lane & 31;   // lane within half

    // stage W1 transposed (vectorized): W1 is [64][128] row-major
    for (int k4 = t; k4 < 64 * 128 / 4; k4 += 256) {
        int k = k4 * 4;
        int j = k >> 7, f = k & 127;
        float4 v = *(const float4*)(W1 + k);
        W1t[f + 0][j] = v.x; W1t[f + 1][j] = v.y;
        W1t[f + 2][j] = v.z; W1t[f + 3][j] = v.w;
    }

    // per-lane W_rbf rows for features 4*hl..4*hl+3
    float wr[4][NR];
#pragma unroll
    for (int c = 0; c < 4; ++c)
#pragma unroll
        for (int r = 0; r < NR; ++r)
            wr[c][r] = W_rbf[(4 * hl + c) * NR + r];

    __syncthreads();

    const int nb = blockIdx.x * 16 + w * 4;

    for (int ta = 0; ta < 2; ++ta) {
        const int n = nb + ta * 2 + h;
        float a0 = 0.f, a1 = 0.f, a2 = 0.f, a3 = 0.f;
        int beg = 0, end = 0;
        if (n < N) { beg = offsets[n]; end = offsets[n + 1]; }

        // 32-deep register cache of this half's edge ids
        int eid = (beg + hl < end) ? sorted[beg + hl] : 0;

        for (int p0 = beg; p0 < end; p0 += 4) {
            int cnt = end - p0; if (cnt > 4) cnt = 4;
            int e4[4];
            float4 mv[4];
            float2 rv[4][3];
#pragma unroll
            for (int k = 0; k < 4; ++k) {
                int off = p0 - beg + k;
                int e;
                if (off < 32) e = __shfl(eid, (h << 5) + off);
                else e = (p0 + k < end) ? sorted[p0 + k] : __shfl(eid, h << 5);
                if (k >= cnt) e = __shfl(eid, h << 5);  // clamp to safe row
                e4[k] = e;
            }
#pragma unroll
            for (int k = 0; k < 4; ++k) {
                mv[k] = *(const float4*)(m + (long)e4[k] * NF + hl * 4);
                long pe = p0 + (k < cnt ? k : 0);
                const float2* rp = (const float2*)(srbf + pe * NR);
                rv[k][0] = rp[0]; rv[k][1] = rp[1]; rv[k][2] = rp[2];
            }
#pragma unroll
            for (int k = 0; k < 4; ++k) {
                if (k < cnt) {
                    float f0 = rv[k][0].x * wr[0][0];
                    float f1 = rv[k][0].x * wr[1][0];
                    float f2 = rv[k][0].x * wr[2][0];
                    float f3 = rv[k][0].x * wr[3][0];
                    f0 = fmaf(rv[k][0].y, wr[0][1], f0);
                    f1 = fmaf(rv[k][0].y, wr[1][1], f1);
                    f2 = fmaf(rv[k][0].y, wr[2][1], f2);
                    f3 = fmaf(rv[k][0].y, wr[3][1], f3);
                    f0 = fmaf(rv[k][1].x, wr[0][2], f0);
                    f1 = fmaf(rv[k][1].x, wr[1][2], f1);
                    f2 = fmaf(rv[k][1].x, wr[2][2], f2);
                    f3 = fmaf(rv[k][1].x, wr[3][2], f3);
                    f0 = fmaf(rv[k][1].y, wr[0][3], f0);
                    f1 = fmaf(rv[k][1].y, wr[1][3], f1);
                    f2 = fmaf(rv[k][1].y, wr[2][3], f2);
                    f3 = fmaf(rv[k][1].y, wr[3][3], f3);
                    f0 = fmaf(rv[k][2].x, wr[0][4], f0);
                    f1 = fmaf(rv[k][2].x, wr[1][4], f1);
                    f2 = fmaf(rv[k][2].x, wr[2][4], f2);
                    f3 = fmaf(rv[k][2].x, wr[3][4], f3);
                    f0 = fmaf(rv[k][2].y, wr[0][5], f0);
                    f1 = fmaf(rv[k][2].y, wr[1][5], f1);
                    f2 = fmaf(rv[k][2].y, wr[2][5], f2);
                    f3 = fmaf(rv[k][2].y, wr[3][5], f3);
                    a0 = fmaf(mv[k].x, f0, a0);
                    a1 = fmaf(mv[k].y, f1, a1);
                    a2 = fmaf(mv[k].z, f2, a2);
                    a3 = fmaf(mv[k].w, f3, a3);
                }
            }
        }

        float s0 = a0 / (1.f + __expf(-a0));
        float s1 = a1 / (1.f + __expf(-a1));
        float s2 = a2 / (1.f + __expf(-a2));
        float s3 = a3 / (1.f + __expf(-a3));
        *(float4*)&sb[w][ta * 2 + h][4 * hl] = make_float4(s0, s1, s2, s3);
    }

    __syncthreads();

    // layer 1: 16-lane group ag = atom (0..3 of this wave), lane lj owns
    // outputs 4*lj..4*lj+3
    const int ag = lane >> 4;
    const int lj = lane & 15;

    float4 bv = *(const float4*)(b1 + 4 * lj);
    float h0 = bv.x, h1 = bv.y, h2 = bv.z, h3 = bv.w;

    for (int f = 0; f < 128; f += 4) {
        float4 sv = *(const float4*)&sb[w][ag][f];
        float4 w0 = *(const float4*)&W1t[f + 0][4 * lj];
        float4 w1v = *(const float4*)&W1t[f + 1][4 * lj];
        float4 w2v = *(const float4*)&W1t[f + 2][4 * lj];
        float4 w3v = *(const float4*)&W1t[f + 3][4 * lj];
        h0 = fmaf(sv.x, w0.x, h0);  h1 = fmaf(sv.x, w0.y, h1);
        h2 = fmaf(sv.x, w0.z, h2);  h3 = fmaf(sv.x, w0.w, h3);
        h0 = fmaf(sv.y, w1v.x, h0); h1 = fmaf(sv.y, w1v.y, h1);
        h2 = fmaf(sv.y, w1v.z, h2); h3 = fmaf(sv.y, w1v.w, h3);
        h0 = fmaf(sv.z, w2v.x, h0); h1 = fmaf(sv.z, w2v.y, h1);
        h2 = fmaf(sv.z, w2v.z, h2); h3 = fmaf(sv.z, w2v.w, h3);
        h0 = fmaf(sv.w, w3v.x, h0); h1 = fmaf(sv.w, w3v.y, h1);
        h2 = fmaf(sv.w, w3v.z, h2); h3 = fmaf(sv.w, w3v.w, h3);
    }

    float4 w2 = *(const float4*)(W2 + 4 * lj);
    float r = (h0 / (1.f + __expf(-h0))) * w2.x
            + (h1 / (1.f + __expf(-h1))) * w2.y
            + (h2 / (1.f + __expf(-h2))) * w2.z
            + (h3 / (1.f + __expf(-h3))) * w2.w;

    r += __shfl_xor(r, 1);
    r += __shfl_xor(r, 2);
    r += __shfl_xor(r, 4);
    r += __shfl_xor(r, 8);

    int n = nb + ag;
    if (lj == 0 && n < N) out[n] = r + b2[0];
}

extern "C" void kernel_launch(void* const* d_in, const int* in_sizes, int n_in,
                              void* d_out, int out_size, void* d_ws, size_t ws_size,
                              hipStream_t stream) {
    const float* m     = (const float*)d_in[0];
    const float* rbf   = (const float*)d_in[1];
    const int*   idx   = (const int*)d_in[2];
    const float* W_rbf = (const float*)d_in[4];
    const float* W1    = (const float*)d_in[5];
    const float* b1    = (const float*)d_in[6];
    const float* W2    = (const float*)d_in[7];
    const float* b2    = (const float*)d_in[8];
    float* out = (float*)d_out;

    const int E = in_sizes[2];   // one atom index per edge
    const int N = out_size;      // out is [N, 1]

    // workspace layout (all segment starts 8B-aligned)
    int* count   = (int*)d_ws;                        // N
    int* offsets = count + N;                         // N+1
    int* cursor  = offsets + ((N + 2) & ~1);          // N
    int* sorted  = cursor + N;                        // E
    float* srbf  = (float*)(sorted + ((E + 1) & ~1)); // 6E floats

    hipMemsetAsync(count, 0, (size_t)N * sizeof(int), stream);

    hist_kernel<<<2048, 256, 0, stream>>>(idx, count, E);
    scan_all_kernel<<<SCAN_BLOCKS, 256, 0, stream>>>(count, offsets, cursor, N);
    reorder_kernel<<<2048, 256, 0, stream>>>(idx, rbf, cursor, sorted, srbf, E);
    gather_mlp_kernel<<<(N + 15) / 16, 256, 0, stream>>>(
        m, offsets, sorted, srbf, W_rbf, W1, b1, W2, b2, out, N);
}